// Round 4
// baseline (284.868 us; speedup 1.0000x reference)
//
#include <hip/hip_runtime.h>

#define NB 32
#define NC 511      // T-1 context positions
#define NK 8        // senses (center)
#define NS 8        // senses (context)
#define ND 300      // embedding dim
#define ND4 75      // float4 per row
#define CHUNK 16    // c's per block
#define NCHK 32     // ceil(NC/CHUNK)
#define EPS_COS 1e-8f

// Math notes (verified R1-R3, absmax 0.0):
//  - positional log-weight is constant (dist>=1 -> exp(-1000*d) underflows ->
//    log(EPS)), cancels in the softmax over c => center_pos/query_token_ids unused.
//  - cosine(cen, m) is scale-invariant in m => softmax normalization and max-
//    subtraction cancel; accumulate unnormalized m~ = sum_c exp(a_c) * v_c.
//  - R3 post-mortem: v/ea round-trips (~40 MB) were ~half the kernel time =>
//    fuse: wave computes v in regs, butterfly-reduces the 8 dots so ALL lanes
//    hold a_k, then accumulates w_k*v_lane into registers. No v/ea arrays.

__device__ __forceinline__ void f4add(float4& a, const float4& b) {
    a.x += b.x; a.y += b.y; a.z += b.z; a.w += b.w;
}
__device__ __forceinline__ void f4fma(float4& a, float s, const float4& b) {
    a.x += s * b.x; a.y += s * b.y; a.z += s * b.z; a.w += s * b.w;
}

// ---------------------------------------------------------------------------
// K1: block = (b, chunk of 16 c's), 4 waves x 4 c's each. Per c: load ctx rows
// (8 senses, float4), mean -> v in regs; dot with cen_k; butterfly-reduce so
// every lane has a_k; acc_k += exp(a_k/sqrt(d)) * v_lane. Cross-wave LDS
// reduce -> one partial m~[8][300] per block. Reads ctx exactly once (157 MB).
// ---------------------------------------------------------------------------
__global__ __launch_bounds__(256) void k_fused(const float* __restrict__ ctx,
                                               const float* __restrict__ cen,
                                               float* __restrict__ part) {
    const int b     = blockIdx.x >> 5;     // /NCHK
    const int chunk = blockIdx.x & 31;
    const int w     = threadIdx.x >> 6;
    const int lane  = threadIdx.x & 63;
    const int i0 = lane;
    const int i1 = lane + 64;
    const bool has1 = (i1 < ND4);          // lanes 0..10 own a second float4

    const float4* cen4 = (const float4*)cen + (size_t)b * NK * ND4;

    float4 acc0[NK] = {};                  // per-lane m~ accumulator (d chunk i0)
    float4 acc1[NK] = {};                  // d chunk i1 (lanes 0..10)

    const int cbase = chunk * CHUNK + w * 4;
#pragma unroll 1
    for (int u = 0; u < 4; ++u) {
        const int c = cbase + u;
        if (c >= NC) continue;             // wave-uniform (last chunk only)

        const float4* ctx4 = (const float4*)ctx + (size_t)(b * NC + c) * NS * ND4;
        float4 s0 = make_float4(0.f, 0.f, 0.f, 0.f);
        float4 s1 = make_float4(0.f, 0.f, 0.f, 0.f);
#pragma unroll
        for (int sj = 0; sj < NS; ++sj) {
            float4 x = ctx4[sj * ND4 + i0];
            f4add(s0, x);
            if (has1) {
                float4 y = ctx4[sj * ND4 + i1];
                f4add(s1, y);
            }
        }
        const float inv = 0.125f;          // 1/S
        s0.x *= inv; s0.y *= inv; s0.z *= inv; s0.w *= inv;
        s1.x *= inv; s1.y *= inv; s1.z *= inv; s1.w *= inv;

        float pk[NK];
#pragma unroll
        for (int k = 0; k < NK; ++k) {
            float4 ca = cen4[k * ND4 + i0];
            float p = ca.x * s0.x + ca.y * s0.y + ca.z * s0.z + ca.w * s0.w;
            if (has1) {
                float4 cb = cen4[k * ND4 + i1];
                p += cb.x * s1.x + cb.y * s1.y + cb.z * s1.z + cb.w * s1.w;
            }
            pk[k] = p;
        }
        // butterfly: every lane ends with the full 64-lane sum
#pragma unroll
        for (int off = 32; off; off >>= 1) {
#pragma unroll
            for (int k = 0; k < NK; ++k) pk[k] += __shfl_xor(pk[k], off);
        }
        const float scale = 0.057735026919f; // 1/sqrt(300)
#pragma unroll
        for (int k = 0; k < NK; ++k) {
            float wk = __expf(pk[k] * scale);
            f4fma(acc0[k], wk, s0);
            if (has1) f4fma(acc1[k], wk, s1);
        }
    }

    // cross-wave reduce in LDS (wave 0 stores, waves 1..3 add)
    __shared__ float lm[NK * ND];          // 9.6 KB
    float4* lm4 = (float4*)lm;
    for (int wv = 0; wv < 4; ++wv) {
        if (w == wv) {
#pragma unroll
            for (int k = 0; k < NK; ++k) {
                if (wv == 0) {
                    lm4[k * ND4 + i0] = acc0[k];
                    if (has1) lm4[k * ND4 + i1] = acc1[k];
                } else {
                    float4 t4 = lm4[k * ND4 + i0];
                    f4add(t4, acc0[k]);
                    lm4[k * ND4 + i0] = t4;
                    if (has1) {
                        float4 u4 = lm4[k * ND4 + i1];
                        f4add(u4, acc1[k]);
                        lm4[k * ND4 + i1] = u4;
                    }
                }
            }
        }
        __syncthreads();
    }

    // one partial per block: part[b][chunk][k][d]
    float4* pp4 = (float4*)(part + ((size_t)(b * NCHK + chunk)) * NK * ND);
    for (int idx = threadIdx.x; idx < NK * ND4; idx += 256)   // 600 float4
        pp4[idx] = lm4[idx];
}

// ---------------------------------------------------------------------------
// K2: per b — sum 32 m~ partials (contiguous 307 KB) into LDS, cosine per k,
// q softmax, first-max argmax, write q and pooled.
// ---------------------------------------------------------------------------
__global__ __launch_bounds__(256) void k_final(const float* __restrict__ part,
                                               const float* __restrict__ cen,
                                               float* __restrict__ out) {
    const int b = blockIdx.x;
    __shared__ float m[NK * ND];
    __shared__ float sred[NK];
    __shared__ int bidx;
    const int t = threadIdx.x;

    const float4* pb = (const float4*)(part + (size_t)b * NCHK * NK * ND);
    float4* m4 = (float4*)m;
    for (int idx = t; idx < NK * ND4; idx += 256) {   // 600 float4
        float4 s = make_float4(0.f, 0.f, 0.f, 0.f);
#pragma unroll
        for (int ch = 0; ch < NCHK; ++ch)
            f4add(s, pb[(size_t)ch * NK * ND4 + idx]);
        m4[idx] = s;
    }
    __syncthreads();

    const int w = t >> 6, lane = t & 63;
#pragma unroll
    for (int kk = 0; kk < 2; ++kk) {
        const int k = w + kk * 4;
        const float* cp = cen + (size_t)(b * NK + k) * ND;
        const float* mp = m + k * ND;
        float num = 0.f, n1 = 0.f, n2 = 0.f;
        for (int dd = lane; dd < ND; dd += 64) {
            float cv = cp[dd], mv = mp[dd];
            num += cv * mv; n1 += cv * cv; n2 += mv * mv;
        }
#pragma unroll
        for (int off = 32; off; off >>= 1) {
            num += __shfl_down(num, off);
            n1  += __shfl_down(n1, off);
            n2  += __shfl_down(n2, off);
        }
        if (lane == 0) {
            float denom = fmaxf(sqrtf(n1), EPS_COS) * fmaxf(sqrtf(n2), EPS_COS);
            sred[k] = num / denom;
        }
    }
    __syncthreads();

    if (t == 0) {
        float mx = sred[0];
#pragma unroll
        for (int k = 1; k < NK; ++k) mx = fmaxf(mx, sred[k]);
        float e[NK], sum = 0.f;
#pragma unroll
        for (int k = 0; k < NK; ++k) { e[k] = __expf(sred[k] - mx); sum += e[k]; }
        float inv = 1.f / sum;
        int best = 0; float bv = sred[0];
#pragma unroll
        for (int k = 1; k < NK; ++k) if (sred[k] > bv) { bv = sred[k]; best = k; }
#pragma unroll
        for (int k = 0; k < NK; ++k)
            out[(size_t)NB * ND + b * NK + k] = e[k] * inv;
        bidx = best;
    }
    __syncthreads();

    const float* src = cen + (size_t)(b * NK + bidx) * ND;
    for (int idx = t; idx < ND; idx += 256)
        out[(size_t)b * ND + idx] = src[idx];
}

extern "C" void kernel_launch(void* const* d_in, const int* in_sizes, int n_in,
                              void* d_out, int out_size, void* d_ws, size_t ws_size,
                              hipStream_t stream) {
    // d_in[0]=center_pos, d_in[1]=query_token_ids: unused (log-weight constant)
    const float* cen = (const float*)d_in[2];   // [B,K,d]
    const float* ctx = (const float*)d_in[3];   // [B,C,S,d]
    float* out = (float*)d_out;                 // pooled [B,d] then q [B,K]

    float* part = (float*)d_ws;                 // [B][NCHK][K][d] = 9.83 MB

    k_fused<<<dim3(NB * NCHK), dim3(256), 0, stream>>>(ctx, cen, part);
    k_final<<<dim3(NB), dim3(256), 0, stream>>>(part, cen, out);
}

// Round 5
// 274.838 us; speedup vs baseline: 1.0365x; 1.0365x over previous
//
#include <hip/hip_runtime.h>

#define NB 32
#define NC 511      // T-1 context positions
#define NK 8        // senses (center)
#define NS 8        // senses (context)
#define ND 300      // embedding dim
#define ND4 75      // float4 per row
#define NCHK 64     // c-chunks (8 c's per block)
#define EPS_COS 1e-8f

// Math notes (verified R1-R4, absmax 0.0):
//  - positional log-weight is constant (dist>=1 -> exp(-1000*d) underflows ->
//    log(EPS)), cancels in softmax over c => center_pos/query_token_ids unused.
//  - cosine(cen,m) is scale-invariant in m => softmax normalization and max-
//    subtraction cancel; accumulate unnormalized m~ = sum_c exp(a_c) * v_c.
//  - R4 post-mortem: fusion correct but latency-bound (817 GB/s, occ 25%).
//    Fix: 1 c per wave (16384 waves), all 16 loads in flight per wave.

__device__ __forceinline__ void f4add(float4& a, const float4& b) {
    a.x += b.x; a.y += b.y; a.z += b.z; a.w += b.w;
}

// ---------------------------------------------------------------------------
// K1: block = (b, chunk of 8 c's), 8 waves x 1 c each. Wave: load 16 float4
// of ctx (8 senses x 2 d-slices), mean -> v in regs; 8 dots vs cen; butterfly
// so all lanes hold a_k; contribution_k = exp(a_k/sqrt(d)) * v. 3-stage LDS
// tree merges 8 waves -> one m~ partial [8][300] per block.
// ---------------------------------------------------------------------------
__global__ __launch_bounds__(512) void k_main(const float* __restrict__ ctx,
                                              const float* __restrict__ cen,
                                              float* __restrict__ part) {
    const int b     = blockIdx.x >> 6;     // / NCHK
    const int chunk = blockIdx.x & 63;
    const int w     = threadIdx.x >> 6;    // wave 0..7
    const int lane  = threadIdx.x & 63;
    const int c     = chunk * 8 + w;       // one c per wave
    const int i0 = lane;
    const int i1 = lane + 64;
    const bool has1 = (i1 < ND4);          // lanes 0..10 own a second float4

    float4 acc0[NK] = {};
    float4 acc1[NK] = {};

    if (c < NC) {                          // wave-uniform (only chunk=63,w=7 idle)
        const float4* ctx4 = (const float4*)ctx + (size_t)(b * NC + c) * NS * ND4;
        const float4* cen4 = (const float4*)cen + (size_t)b * NK * ND4;

        float4 s0 = make_float4(0.f, 0.f, 0.f, 0.f);
        float4 s1 = make_float4(0.f, 0.f, 0.f, 0.f);
#pragma unroll
        for (int sj = 0; sj < NS; ++sj) {
            f4add(s0, ctx4[sj * ND4 + i0]);
            if (has1) f4add(s1, ctx4[sj * ND4 + i1]);
        }
        const float inv = 0.125f;          // 1/S
        s0.x *= inv; s0.y *= inv; s0.z *= inv; s0.w *= inv;
        s1.x *= inv; s1.y *= inv; s1.z *= inv; s1.w *= inv;

        float pk[NK];
#pragma unroll
        for (int k = 0; k < NK; ++k) {
            float4 ca = cen4[k * ND4 + i0];
            float p = ca.x * s0.x + ca.y * s0.y + ca.z * s0.z + ca.w * s0.w;
            if (has1) {
                float4 cb = cen4[k * ND4 + i1];
                p += cb.x * s1.x + cb.y * s1.y + cb.z * s1.z + cb.w * s1.w;
            }
            pk[k] = p;
        }
        // butterfly: every lane ends with the full 64-lane dot
#pragma unroll
        for (int off = 32; off; off >>= 1) {
#pragma unroll
            for (int k = 0; k < NK; ++k) pk[k] += __shfl_xor(pk[k], off);
        }
        const float scale = 0.057735026919f; // 1/sqrt(300)
#pragma unroll
        for (int k = 0; k < NK; ++k) {
            float wk = __expf(pk[k] * scale);
            acc0[k].x = wk * s0.x; acc0[k].y = wk * s0.y;
            acc0[k].z = wk * s0.z; acc0[k].w = wk * s0.w;
            acc1[k].x = wk * s1.x; acc1[k].y = wk * s1.y;
            acc1[k].z = wk * s1.z; acc1[k].w = wk * s1.w;
        }
    }

    // ---- 3-stage tree reduce over 8 waves (slabs: 4,2,1 of [NK][ND4]) ----
    __shared__ float4 slab[4 * NK * ND4];  // 38.4 KB
#define SLAB_ST(slot) { float4* sp = slab + (slot) * NK * ND4;                  \
    _Pragma("unroll") for (int k = 0; k < NK; ++k) {                            \
        sp[k * ND4 + i0] = acc0[k];                                             \
        if (has1) sp[k * ND4 + i1] = acc1[k]; } }
#define SLAB_ADD(slot) { const float4* sp = slab + (slot) * NK * ND4;           \
    _Pragma("unroll") for (int k = 0; k < NK; ++k) {                            \
        f4add(acc0[k], sp[k * ND4 + i0]);                                       \
        if (has1) f4add(acc1[k], sp[k * ND4 + i1]); } }

    if (w >= 4) SLAB_ST(w - 4);
    __syncthreads();
    if (w < 4) SLAB_ADD(w);
    __syncthreads();
    if (w == 2 || w == 3) SLAB_ST(w - 2);
    __syncthreads();
    if (w < 2) SLAB_ADD(w);
    __syncthreads();
    if (w == 1) SLAB_ST(0);
    __syncthreads();
    if (w == 0) {
        SLAB_ADD(0);
        float4* pp = (float4*)part + (size_t)(b * NCHK + chunk) * NK * ND4;
#pragma unroll
        for (int k = 0; k < NK; ++k) {
            pp[k * ND4 + i0] = acc0[k];
            if (has1) pp[k * ND4 + i1] = acc1[k];
        }
    }
#undef SLAB_ST
#undef SLAB_ADD
}

// ---------------------------------------------------------------------------
// K2: block = (b,k), 320 threads. Sum 64 chunk-partials along d, then block-
// reduce the cosine terms -> s[b,k].
// ---------------------------------------------------------------------------
__global__ __launch_bounds__(320) void k_red(const float* __restrict__ part,
                                             const float* __restrict__ cen,
                                             float* __restrict__ sv) {
    const int b = blockIdx.x >> 3;
    const int k = blockIdx.x & 7;
    const int t = threadIdx.x;
    const int lane = t & 63, w = t >> 6;

    float m = 0.f;
    float cv = 0.f;
    if (t < ND) {
        const float* p = part + ((size_t)b * NCHK * NK + k) * ND + t;
#pragma unroll 4
        for (int ch = 0; ch < NCHK; ++ch)
            m += p[(size_t)ch * NK * ND];
        cv = cen[(size_t)(b * NK + k) * ND + t];
    }
    float num = cv * m, n1 = cv * cv, n2 = m * m;
#pragma unroll
    for (int off = 32; off; off >>= 1) {
        num += __shfl_down(num, off);
        n1  += __shfl_down(n1, off);
        n2  += __shfl_down(n2, off);
    }
    __shared__ float red[5][3];
    if (lane == 0) { red[w][0] = num; red[w][1] = n1; red[w][2] = n2; }
    __syncthreads();
    if (t == 0) {
        float a0 = 0.f, a1 = 0.f, a2 = 0.f;
#pragma unroll
        for (int i = 0; i < 5; ++i) { a0 += red[i][0]; a1 += red[i][1]; a2 += red[i][2]; }
        float denom = fmaxf(sqrtf(a1), EPS_COS) * fmaxf(sqrtf(a2), EPS_COS);
        sv[b * NK + k] = a0 / denom;
    }
}

// ---------------------------------------------------------------------------
// K3: per b — q softmax over 8, first-max argmax, write q and pooled row.
// ---------------------------------------------------------------------------
__global__ __launch_bounds__(256) void k_fin(const float* __restrict__ sv,
                                             const float* __restrict__ cen,
                                             float* __restrict__ out) {
    const int b = blockIdx.x;
    const int t = threadIdx.x;
    __shared__ int bidx;
    if (t == 0) {
        float s[NK];
#pragma unroll
        for (int k = 0; k < NK; ++k) s[k] = sv[b * NK + k];
        float mx = s[0];
#pragma unroll
        for (int k = 1; k < NK; ++k) mx = fmaxf(mx, s[k]);
        float e[NK], sum = 0.f;
#pragma unroll
        for (int k = 0; k < NK; ++k) { e[k] = __expf(s[k] - mx); sum += e[k]; }
        float inv = 1.f / sum;
        int best = 0; float bv = s[0];
#pragma unroll
        for (int k = 1; k < NK; ++k) if (s[k] > bv) { bv = s[k]; best = k; }
#pragma unroll
        for (int k = 0; k < NK; ++k)
            out[(size_t)NB * ND + b * NK + k] = e[k] * inv;
        bidx = best;
    }
    __syncthreads();
    const float* src = cen + (size_t)(b * NK + bidx) * ND;
    for (int idx = t; idx < ND; idx += 256)
        out[(size_t)b * ND + idx] = src[idx];
}

extern "C" void kernel_launch(void* const* d_in, const int* in_sizes, int n_in,
                              void* d_out, int out_size, void* d_ws, size_t ws_size,
                              hipStream_t stream) {
    // d_in[0]=center_pos, d_in[1]=query_token_ids: unused (log-weight constant)
    const float* cen = (const float*)d_in[2];   // [B,K,d]
    const float* ctx = (const float*)d_in[3];   // [B,C,S,d]
    float* out = (float*)d_out;                 // pooled [B,d] then q [B,K]

    float* part = (float*)d_ws;                        // [B][NCHK][K][d] = 19.66 MB
    float* sv   = part + (size_t)NB * NCHK * NK * ND;  // [B][K]

    k_main<<<dim3(NB * NCHK), dim3(512), 0, stream>>>(ctx, cen, part);
    k_red<<<dim3(NB * NK), dim3(320), 0, stream>>>(part, cen, sv);
    k_fin<<<dim3(NB), dim3(256), 0, stream>>>(sv, cen, out);
}

// Round 6
// 257.521 us; speedup vs baseline: 1.1062x; 1.0672x over previous
//
#include <hip/hip_runtime.h>

#define NB 32
#define NC 511      // T-1 context positions
#define NK 8        // senses (center)
#define NS 8        // senses (context)
#define ND 300      // embedding dim
#define ND4 75      // float4 per row
#define CPB 8       // c's per staged tile (8*9600 B = exactly 75 KiB)
#define NTILE 4     // tiles per block
#define NJ 16       // blocks per b  (NJ*NTILE*CPB = 512 >= NC)
#define NCHK 16     // m~ partials per b (one per block)
#define EPS_COS 1e-8f
#define CTX_FLOATS ((size_t)NB * NC * NS * ND)   // 39,244,800

// Math notes (verified R1-R5, absmax 0.0):
//  - positional log-weight is constant (dist>=1 -> exp(-1000*d) underflows ->
//    log(EPS)), cancels in softmax over c => center_pos/query_token_ids unused.
//  - cosine(cen,m) is scale-invariant in m => softmax normalization and max-
//    subtraction cancel; accumulate unnormalized m~ = sum_c exp(a_c) * v_c.
//  - R5 post-mortem: latency-bound at 1.55 TB/s logical; VGPR_Count=56 proves
//    only ~8 loads in flight/wave (dest-VGPR limited). Fix: global_load_lds
//    async DMA staging — MLP lives in the memory pipe, not the register file.

__device__ __forceinline__ void f4add(float4& a, const float4& b) {
    a.x += b.x; a.y += b.y; a.z += b.z; a.w += b.w;
}

// ---------------------------------------------------------------------------
// K1: block = (b, j). Loop over 4 tiles of 8 c's: DMA-stage 75 KiB of ctx
// into LDS (global_load_lds width 16, wave-uniform base + lane*16 contiguous
// — layout is pure contiguous copy, the one pattern this instr supports),
// barrier (drains vmcnt), wave w computes c = c0+w from LDS: mean over
// senses -> v; 8 dots vs cen; butterfly so all lanes hold a_k;
// acc_k += exp(a_k/sqrt(d)) * v. After 4 tiles: 3-stage LDS tree merge
// (reusing the staging buffer) -> one m~ partial per block.
// 512 blocks = 2/CU (LDS-limited): B's compute overlaps A's DMA drain.
// ---------------------------------------------------------------------------
__global__ __launch_bounds__(512, 4) void k_main(const float* __restrict__ ctx,
                                                 const float* __restrict__ cen,
                                                 float* __restrict__ part) {
    const int b    = blockIdx.x >> 4;
    const int j    = blockIdx.x & 15;
    const int w    = threadIdx.x >> 6;     // wave 0..7
    const int lane = threadIdx.x & 63;
    const int i0 = lane;
    const int i1 = lane + 64;
    const bool has1 = (i1 < ND4);          // lanes 0..10 own a second float4

    __shared__ float4 sh4[4800];           // 76.8 KB: staging tile / tree slabs
    float* sh = (float*)sh4;

    float4 acc0[NK] = {};
    float4 acc1[NK] = {};
    const float4* cen4 = (const float4*)cen + (size_t)b * NK * ND4;
    const float* gmax = ctx + CTX_FLOATS - 4;   // last valid 16B load base

#pragma unroll 1
    for (int t = 0; t < NTILE; ++t) {
        const int c0 = (j * NTILE + t) * CPB;
        const float* gbase = ctx + ((size_t)b * NC + c0) * (NS * ND);

        // ---- async DMA stage: 75 segments x 1 KiB; waves round-robin ----
        for (int seg = w; seg < 75; seg += 8) {
            const float* ga = gbase + seg * 256 + lane * 4;
            if (ga > gmax) ga = gmax;      // clamp tail (c=511 slot, ignored)
            __builtin_amdgcn_global_load_lds(
                (const __attribute__((address_space(1))) void*)ga,
                (__attribute__((address_space(3))) void*)(sh + seg * 256),
                16, 0, 0);
        }
        __syncthreads();                   // vmcnt(0) drain + barrier

        // ---- compute: wave w owns c = c0 + w ----
        const int c = c0 + w;
        if (c < NC) {                      // wave-uniform
            const float4* Lw = (const float4*)(sh + w * (NS * ND));
            float4 s0 = make_float4(0.f, 0.f, 0.f, 0.f);
            float4 s1 = make_float4(0.f, 0.f, 0.f, 0.f);
#pragma unroll
            for (int sj = 0; sj < NS; ++sj) {
                f4add(s0, Lw[sj * ND4 + i0]);
                if (has1) f4add(s1, Lw[sj * ND4 + i1]);
            }
            const float inv = 0.125f;      // 1/S
            s0.x *= inv; s0.y *= inv; s0.z *= inv; s0.w *= inv;
            s1.x *= inv; s1.y *= inv; s1.z *= inv; s1.w *= inv;

            float pk[NK];
#pragma unroll
            for (int k = 0; k < NK; ++k) {
                float4 ca = cen4[k * ND4 + i0];
                float p = ca.x * s0.x + ca.y * s0.y + ca.z * s0.z + ca.w * s0.w;
                if (has1) {
                    float4 cb = cen4[k * ND4 + i1];
                    p += cb.x * s1.x + cb.y * s1.y + cb.z * s1.z + cb.w * s1.w;
                }
                pk[k] = p;
            }
#pragma unroll
            for (int off = 32; off; off >>= 1) {
#pragma unroll
                for (int k = 0; k < NK; ++k) pk[k] += __shfl_xor(pk[k], off);
            }
            const float scale = 0.057735026919f; // 1/sqrt(300)
#pragma unroll
            for (int k = 0; k < NK; ++k) {
                float wk = __expf(pk[k] * scale);
                acc0[k].x += wk * s0.x; acc0[k].y += wk * s0.y;
                acc0[k].z += wk * s0.z; acc0[k].w += wk * s0.w;
                if (has1) {
                    acc1[k].x += wk * s1.x; acc1[k].y += wk * s1.y;
                    acc1[k].z += wk * s1.z; acc1[k].w += wk * s1.w;
                }
            }
        }
        __syncthreads();                   // before next tile overwrites LDS
    }

    // ---- 3-stage tree reduce over 8 waves (slabs reuse staging LDS) ----
    float4* slab = sh4;
#define SLAB_ST(slot) { float4* sp = slab + (slot) * NK * ND4;                  \
    _Pragma("unroll") for (int k = 0; k < NK; ++k) {                            \
        sp[k * ND4 + i0] = acc0[k];                                             \
        if (has1) sp[k * ND4 + i1] = acc1[k]; } }
#define SLAB_ADD(slot) { const float4* sp = slab + (slot) * NK * ND4;           \
    _Pragma("unroll") for (int k = 0; k < NK; ++k) {                            \
        f4add(acc0[k], sp[k * ND4 + i0]);                                       \
        if (has1) f4add(acc1[k], sp[k * ND4 + i1]); } }

    if (w >= 4) SLAB_ST(w - 4);
    __syncthreads();
    if (w < 4) SLAB_ADD(w);
    __syncthreads();
    if (w == 2 || w == 3) SLAB_ST(w - 2);
    __syncthreads();
    if (w < 2) SLAB_ADD(w);
    __syncthreads();
    if (w == 1) SLAB_ST(0);
    __syncthreads();
    if (w == 0) {
        SLAB_ADD(0);
        float4* pp = (float4*)part + (size_t)(b * NJ + j) * NK * ND4;
#pragma unroll
        for (int k = 0; k < NK; ++k) {
            pp[k * ND4 + i0] = acc0[k];
            if (has1) pp[k * ND4 + i1] = acc1[k];
        }
    }
#undef SLAB_ST
#undef SLAB_ADD
}

// ---------------------------------------------------------------------------
// K2: block = (b,k), 320 threads. Sum 16 chunk-partials along d, then block-
// reduce the cosine terms -> s[b,k].
// ---------------------------------------------------------------------------
__global__ __launch_bounds__(320) void k_red(const float* __restrict__ part,
                                             const float* __restrict__ cen,
                                             float* __restrict__ sv) {
    const int b = blockIdx.x >> 3;
    const int k = blockIdx.x & 7;
    const int t = threadIdx.x;
    const int lane = t & 63, w = t >> 6;

    float m = 0.f;
    float cv = 0.f;
    if (t < ND) {
        const float* p = part + ((size_t)(b * NCHK) * NK + k) * ND + t;
#pragma unroll
        for (int ch = 0; ch < NCHK; ++ch)
            m += p[(size_t)ch * NK * ND];
        cv = cen[(size_t)(b * NK + k) * ND + t];
    }
    float num = cv * m, n1 = cv * cv, n2 = m * m;
#pragma unroll
    for (int off = 32; off; off >>= 1) {
        num += __shfl_down(num, off);
        n1  += __shfl_down(n1, off);
        n2  += __shfl_down(n2, off);
    }
    __shared__ float red[5][3];
    if (lane == 0) { red[w][0] = num; red[w][1] = n1; red[w][2] = n2; }
    __syncthreads();
    if (t == 0) {
        float a0 = 0.f, a1 = 0.f, a2 = 0.f;
#pragma unroll
        for (int i = 0; i < 5; ++i) { a0 += red[i][0]; a1 += red[i][1]; a2 += red[i][2]; }
        float denom = fmaxf(sqrtf(a1), EPS_COS) * fmaxf(sqrtf(a2), EPS_COS);
        sv[b * NK + k] = a0 / denom;
    }
}

// ---------------------------------------------------------------------------
// K3: per b — q softmax over 8, first-max argmax, write q and pooled row.
// ---------------------------------------------------------------------------
__global__ __launch_bounds__(256) void k_fin(const float* __restrict__ sv,
                                             const float* __restrict__ cen,
                                             float* __restrict__ out) {
    const int b = blockIdx.x;
    const int t = threadIdx.x;
    __shared__ int bidx;
    if (t == 0) {
        float s[NK];
#pragma unroll
        for (int k = 0; k < NK; ++k) s[k] = sv[b * NK + k];
        float mx = s[0];
#pragma unroll
        for (int k = 1; k < NK; ++k) mx = fmaxf(mx, s[k]);
        float e[NK], sum = 0.f;
#pragma unroll
        for (int k = 0; k < NK; ++k) { e[k] = __expf(s[k] - mx); sum += e[k]; }
        float inv = 1.f / sum;
        int best = 0; float bv = s[0];
#pragma unroll
        for (int k = 1; k < NK; ++k) if (s[k] > bv) { bv = s[k]; best = k; }
#pragma unroll
        for (int k = 0; k < NK; ++k)
            out[(size_t)NB * ND + b * NK + k] = e[k] * inv;
        bidx = best;
    }
    __syncthreads();
    const float* src = cen + (size_t)(b * NK + bidx) * ND;
    for (int idx = t; idx < ND; idx += 256)
        out[(size_t)b * ND + idx] = src[idx];
}

extern "C" void kernel_launch(void* const* d_in, const int* in_sizes, int n_in,
                              void* d_out, int out_size, void* d_ws, size_t ws_size,
                              hipStream_t stream) {
    // d_in[0]=center_pos, d_in[1]=query_token_ids: unused (log-weight constant)
    const float* cen = (const float*)d_in[2];   // [B,K,d]
    const float* ctx = (const float*)d_in[3];   // [B,C,S,d]
    float* out = (float*)d_out;                 // pooled [B,d] then q [B,K]

    float* part = (float*)d_ws;                        // [B][NCHK][K][d] = 4.9 MB
    float* sv   = part + (size_t)NB * NCHK * NK * ND;  // [B][K]

    k_main<<<dim3(NB * NJ), dim3(512), 0, stream>>>(ctx, cen, part);
    k_red<<<dim3(NB * NK), dim3(320), 0, stream>>>(part, cen, sv);
    k_fin<<<dim3(NB), dim3(256), 0, stream>>>(sv, cen, out);
}

// Round 8
// 247.771 us; speedup vs baseline: 1.1497x; 1.0394x over previous
//
#include <hip/hip_runtime.h>

#define NB 32
#define NC 511      // T-1 context positions
#define NK 8        // senses (center)
#define NS 8        // senses (context)
#define ND 300      // embedding dim
#define ND4 75      // float4 per row
#define NCH 16      // c-chunks for m-tilde partials
#define CCHUNK 32
#define EPS_COS 1e-8f

// Math notes (verified R1-R6, absmax 0.0):
//  - positional log-weight is constant (dist>=1 -> exp(-1000*d) underflows ->
//    log(EPS)), cancels in softmax over c => center_pos/query_token_ids unused.
//  - cosine(cen,m) is scale-invariant in m => softmax normalization and max-
//    subtraction cancel; accumulate unnormalized m~ = sum_c exp(a_c) * v_c.
//  - R6 post-mortem: every structure plateaus at 1.8-2.5 TB/s logical reads.
//    R8 experiment (R7 intent, compile-fixed): R3 structure, k_va loads
//    batched (8 unmasked, then ONE exec-toggle block of 8 tails, no
//    interleaved arithmetic) + nontemporal via ext_vector_type (the builtin
//    rejects HIP_vector_type pointers).

typedef float nfloat4 __attribute__((ext_vector_type(4)));

__device__ __forceinline__ void f4add(float4& a, const float4& b) {
    a.x += b.x; a.y += b.y; a.z += b.z; a.w += b.w;
}
__device__ __forceinline__ void n4add(nfloat4& a, const nfloat4& b) { a += b; }

// ---------------------------------------------------------------------------
// K1: one wave per (b,c). Batched NT loads -> tree mean -> v; 8 dots vs cen;
// butterfly; ea = exp(a/sqrt(d)). Reads ctx once (157 MB) — the BW-critical pass.
// ---------------------------------------------------------------------------
__global__ __launch_bounds__(256) void k_va(const float* __restrict__ ctx,
                                            const float* __restrict__ cen,
                                            float* __restrict__ v,
                                            float* __restrict__ ea) {
    const int b    = blockIdx.x >> 7;        // 128 blocks per b
    const int cgrp = blockIdx.x & 127;
    const int w    = threadIdx.x >> 6;       // 4 waves -> 4 c's
    const int lane = threadIdx.x & 63;
    const int c = cgrp * 4 + w;
    if (c >= NC) return;                     // wave-uniform

    const nfloat4* ctx4 = (const nfloat4*)ctx + (size_t)(b * NC + c) * NS * ND4;
    const int i0 = lane;
    const int i1 = lane + 64;
    const bool has1 = (i1 < ND4);            // lanes 0..10 own a second float4

    // ---- batched loads: 8 unmasked, then one exec-toggle block of 8 ----
    nfloat4 X[NS];
#pragma unroll
    for (int s = 0; s < NS; ++s)
        X[s] = __builtin_nontemporal_load(&ctx4[s * ND4 + i0]);
    nfloat4 Y[NS] = {};
    if (has1) {
#pragma unroll
        for (int s = 0; s < NS; ++s)
            Y[s] = __builtin_nontemporal_load(&ctx4[s * ND4 + i1]);
    }

    // ---- tree mean ----
    n4add(X[0], X[1]); n4add(X[2], X[3]); n4add(X[4], X[5]); n4add(X[6], X[7]);
    n4add(X[0], X[2]); n4add(X[4], X[6]);
    n4add(X[0], X[4]);
    n4add(Y[0], Y[1]); n4add(Y[2], Y[3]); n4add(Y[4], Y[5]); n4add(Y[6], Y[7]);
    n4add(Y[0], Y[2]); n4add(Y[4], Y[6]);
    n4add(Y[0], Y[4]);
    const float inv = 0.125f;                // 1/S
    nfloat4 s0 = X[0] * inv;
    nfloat4 s1 = Y[0] * inv;

    nfloat4* v4 = (nfloat4*)v + (size_t)(b * NC + c) * ND4;
    v4[i0] = s0;
    if (has1) v4[i1] = s1;

    // ---- 8 dots vs cen (L1-resident after first block) ----
    const nfloat4* cen4 = (const nfloat4*)cen + (size_t)b * NK * ND4;
    float pk[NK];
#pragma unroll
    for (int k = 0; k < NK; ++k) {
        nfloat4 ca = cen4[k * ND4 + i0];
        float p = ca.x * s0.x + ca.y * s0.y + ca.z * s0.z + ca.w * s0.w;
        if (has1) {
            nfloat4 cb = cen4[k * ND4 + i1];
            p += cb.x * s1.x + cb.y * s1.y + cb.z * s1.z + cb.w * s1.w;
        }
        pk[k] = p;
    }
#pragma unroll
    for (int off = 32; off; off >>= 1) {
#pragma unroll
        for (int k = 0; k < NK; ++k) pk[k] += __shfl_down(pk[k], off);
    }
    if (lane == 0) {
        const float scale = 0.057735026919f; // 1/sqrt(300)
#pragma unroll
        for (int k = 0; k < NK; ++k)
            ea[(size_t)(b * NK + k) * NC + c] = __expf(pk[k] * scale);
    }
}

// ---------------------------------------------------------------------------
// K2: m~ partials over c-chunks: part[ch,b,k,:] = sum_{c in chunk} ea * v[b,c,:].
// 512 blocks (2/CU); ea tile in LDS (broadcast reads). v is L2/L3-warm.
// ---------------------------------------------------------------------------
__global__ __launch_bounds__(320) void k_m(const float* __restrict__ v,
                                           const float* __restrict__ ea,
                                           float* __restrict__ part) {
    int b  = blockIdx.x >> 4;
    int ch = blockIdx.x & 15;
    int c0 = ch * CCHUNK;
    int cn = min(CCHUNK, NC - c0);
    __shared__ float al[NK][CCHUNK];
    int t = threadIdx.x;
    if (t < NK * CCHUNK) {             // 256 loads
        int k = t >> 5, cc = t & 31;
        al[k][cc] = (cc < cn) ? ea[(size_t)(b * NK + k) * NC + c0 + cc] : 0.f;
    }
    __syncthreads();
    if (t < ND) {
        float acc[NK] = {0.f, 0.f, 0.f, 0.f, 0.f, 0.f, 0.f, 0.f};
        const float* vp = v + ((size_t)b * NC + c0) * ND + t;
        for (int cc = 0; cc < cn; ++cc) {
            float vv = vp[(size_t)cc * ND];
#pragma unroll
            for (int k = 0; k < NK; ++k) acc[k] += al[k][cc] * vv;
        }
        float* pp = part + ((size_t)(ch * NB + b) * NK) * ND + t;
#pragma unroll
        for (int k = 0; k < NK; ++k) pp[(size_t)k * ND] = acc[k];
    }
}

// ---------------------------------------------------------------------------
// K3: per b — sum m~ partials into LDS, cosine per k (wave w: k=w, w+4),
// q softmax, first-max argmax, write q and pooled.
// ---------------------------------------------------------------------------
__global__ __launch_bounds__(256) void k_final(const float* __restrict__ part,
                                               const float* __restrict__ cen,
                                               float* __restrict__ out) {
    int b = blockIdx.x;
    __shared__ float m[NK * ND];
    __shared__ float sred[NK];
    __shared__ int bidx;
    int t = threadIdx.x;

    for (int idx = t; idx < NK * ND; idx += 256) {
        float s = 0.f;
#pragma unroll
        for (int ch = 0; ch < NCH; ++ch)
            s += part[(size_t)(ch * NB + b) * NK * ND + idx];
        m[idx] = s;
    }
    __syncthreads();

    int w = t >> 6, lane = t & 63;
#pragma unroll
    for (int kk = 0; kk < 2; ++kk) {
        int k = w + kk * 4;
        const float* cp = cen + (size_t)(b * NK + k) * ND;
        const float* mp = m + k * ND;
        float num = 0.f, n1 = 0.f, n2 = 0.f;
        for (int dd = lane; dd < ND; dd += 64) {
            float cv = cp[dd], mv = mp[dd];
            num += cv * mv; n1 += cv * cv; n2 += mv * mv;
        }
#pragma unroll
        for (int off = 32; off; off >>= 1) {
            num += __shfl_down(num, off);
            n1  += __shfl_down(n1, off);
            n2  += __shfl_down(n2, off);
        }
        if (lane == 0) {
            float denom = fmaxf(sqrtf(n1), EPS_COS) * fmaxf(sqrtf(n2), EPS_COS);
            sred[k] = num / denom;
        }
    }
    __syncthreads();

    if (t == 0) {
        float mx = sred[0];
#pragma unroll
        for (int k = 1; k < NK; ++k) mx = fmaxf(mx, sred[k]);
        float e[NK], sum = 0.f;
#pragma unroll
        for (int k = 0; k < NK; ++k) { e[k] = __expf(sred[k] - mx); sum += e[k]; }
        float inv = 1.f / sum;
        int best = 0; float bv = sred[0];
#pragma unroll
        for (int k = 1; k < NK; ++k) if (sred[k] > bv) { bv = sred[k]; best = k; }
#pragma unroll
        for (int k = 0; k < NK; ++k)
            out[(size_t)NB * ND + b * NK + k] = e[k] * inv;
        bidx = best;
    }
    __syncthreads();

    const float* src = cen + (size_t)(b * NK + bidx) * ND;
    for (int idx = t; idx < ND; idx += 256)
        out[(size_t)b * ND + idx] = src[idx];
}

extern "C" void kernel_launch(void* const* d_in, const int* in_sizes, int n_in,
                              void* d_out, int out_size, void* d_ws, size_t ws_size,
                              hipStream_t stream) {
    // d_in[0]=center_pos, d_in[1]=query_token_ids: unused (log-weight constant)
    const float* cen = (const float*)d_in[2];   // [B,K,d]
    const float* ctx = (const float*)d_in[3];   // [B,C,S,d]
    float* out = (float*)d_out;                 // pooled [B,d] then q [B,K]

    float* v    = (float*)d_ws;                      // B*C*D     floats
    float* ea   = v + (size_t)NB * NC * ND;          // B*K*C     floats
    float* part = ea + (size_t)NB * NK * NC;         // NCH*B*K*D floats

    k_va<<<dim3(NB * 128), dim3(256), 0, stream>>>(ctx, cen, v, ea);
    k_m<<<dim3(NB * NCH), dim3(320), 0, stream>>>(v, ea, part);
    k_final<<<dim3(NB), dim3(256), 0, stream>>>(part, cen, out);
}